// Round 6
// baseline (515.291 us; speedup 1.0000x reference)
//
#include <hip/hip_runtime.h>
#include <math.h>

// ---------------------------------------------------------------------------
// GaussianQuant — MFMA-filtered argmax, R6.
// score[n,k] = sum_d p*c + q*c^2;  u=[p,q], v=[c,c^2], score = u.v  (K=64)
// fp16 hi/lo split (lo x2048):  s ~= uh.vh + (ul.vh + uh.vl)/2048
// Rigorous |err| <= B = 5e-6*S + 1e-4,  S = sum |p|M1 + |q|M2.
// Filter (NSPLIT=16): per (row, split) keep top1(a1,idx)+top2(a2) via
// epilogue shuffle-reduce over c16. Merge: T = maxA* - 2B; exact-rescore
// winners with a1>=T, full-rescan slices with a2>=T (sound superset).
// ---------------------------------------------------------------------------

typedef _Float16 half8 __attribute__((ext_vector_type(8)));
typedef float f32x4 __attribute__((ext_vector_type(4)));

#define DIM 32
#define NTOK 2048
#define NROWS 16384
#define KSIZE 16384
#define NSPLIT 16
#define SPLITK (KSIZE / NSPLIT)        // 1024
#define NTILES (SPLITK / 16)           // 64

// ws layout (bytes)
#define WS_M1   0                       // 32 float (memset 0)
#define WS_M2   128                     // 32 float
#define WS_PART 512                     // 256 double
#define WS_PQ   4096                    // 16384*64*4 = 4 MB
#define WS_BN   (WS_PQ + 4194304)       // 64 KB
#define WS_AH   (WS_BN + 65536)         // 2 MB fp16
#define WS_AL   (WS_AH + 2097152)       // 2 MB
#define WS_BH   (WS_AL + 2097152)       // 2 MB
#define WS_BL   (WS_BH + 2097152)       // 2 MB
#define WS_W1   (WS_BL + 2097152)       // 16384*16*4 = 1 MB
#define WS_W2   (WS_W1 + 1048576)       // 1 MB
#define WS_I1   (WS_W2 + 1048576)       // 1 MB
#define WS_IDX  (WS_I1 + 1048576)       // 64 KB

__global__ __launch_bounds__(256) void kl_kernel(const float* __restrict__ z,
                                                 double* __restrict__ partials) {
  const int tid = threadIdx.x;
  const int lane = tid & 63;
  const int wave = tid >> 6;
  double s = 0.0;
  for (int j = blockIdx.x * 256 + tid; j < NTOK * 256; j += 256 * 256) {
    const int t = j >> 8, r = j & 255;
    float mu = z[t * 512 + r];
    float lv = z[t * 512 + 256 + r];
    lv = fminf(fmaxf(lv, -30.0f), 20.0f);
    float var = expf(lv);
    s += (double)(mu * mu + var - 1.0f - lv);
  }
  for (int off = 32; off > 0; off >>= 1) s += __shfl_down(s, off);
  __shared__ double wsum[4];
  if (lane == 0) wsum[wave] = s;
  __syncthreads();
  if (tid == 0) partials[blockIdx.x] = (wsum[0] + wsum[1]) + (wsum[2] + wsum[3]);
}

__global__ __launch_bounds__(64) void cbprep_kernel(const float* __restrict__ cb,
                                                    _Float16* __restrict__ Bh,
                                                    _Float16* __restrict__ Bl,
                                                    float* __restrict__ M1,
                                                    float* __restrict__ M2) {
  __shared__ unsigned lm1[DIM], lm2[DIM];
  if (threadIdx.x < DIM) { lm1[threadIdx.x] = 0u; lm2[threadIdx.x] = 0u; }
  __syncthreads();
  const int k = blockIdx.x * 64 + threadIdx.x;
  _Float16 bh[64], bl[64];
#pragma unroll
  for (int d = 0; d < DIM; ++d) {
    float c = cb[k * DIM + d];
    float c2 = c * c;
    _Float16 ch = (_Float16)c;
    _Float16 cl = (_Float16)((c - (float)ch) * 2048.0f);
    _Float16 sh = (_Float16)c2;
    _Float16 sl = (_Float16)((c2 - (float)sh) * 2048.0f);
    bh[d] = ch; bh[32 + d] = sh;
    bl[d] = cl; bl[32 + d] = sl;
    atomicMax(&lm1[d], __float_as_uint(fabsf(c)));
    atomicMax(&lm2[d], __float_as_uint(c2));
  }
#pragma unroll
  for (int i = 0; i < 8; ++i) {
    half8 vh, vl;
#pragma unroll
    for (int j = 0; j < 8; ++j) { vh[j] = bh[i * 8 + j]; vl[j] = bl[i * 8 + j]; }
    *(half8*)(Bh + (size_t)k * 64 + i * 8) = vh;
    *(half8*)(Bl + (size_t)k * 64 + i * 8) = vl;
  }
  __syncthreads();
  if (threadIdx.x < DIM) {
    atomicMax((unsigned*)&M1[threadIdx.x], lm1[threadIdx.x]);
    atomicMax((unsigned*)&M2[threadIdx.x], lm2[threadIdx.x]);
  }
}

__global__ __launch_bounds__(64) void aprep_kernel(const float* __restrict__ z,
                                                   const float* __restrict__ M1,
                                                   const float* __restrict__ M2,
                                                   float* __restrict__ PQ,
                                                   _Float16* __restrict__ Ah,
                                                   _Float16* __restrict__ Al,
                                                   float* __restrict__ Bn) {
  const int row = blockIdx.x * 64 + threadIdx.x;
  const int t = row >> 3, c = row & 7;
  _Float16 ah[64], al[64];
  float S = 0.0f;
#pragma unroll
  for (int d = 0; d < DIM; ++d) {
    float mu = z[t * 512 + d * 8 + c];
    float lv = z[t * 512 + 256 + d * 8 + c];
    lv = fminf(fmaxf(lv, -30.0f), 20.0f);
    float stdv = expf(0.5f * lv);
    float iv = 1.0f / (stdv * stdv);          // identical to R2 expression
    float p = mu * iv;
    float q = 0.5f * (1.0f - iv);
    PQ[(size_t)row * 64 + d] = p;
    PQ[(size_t)row * 64 + 32 + d] = q;
    S += fabsf(p) * M1[d] + fabsf(q) * M2[d];
    _Float16 ph = (_Float16)p;
    _Float16 qh = (_Float16)q;
    ah[d] = ph;       al[d] = (_Float16)((p - (float)ph) * 2048.0f);
    ah[32 + d] = qh;  al[32 + d] = (_Float16)((q - (float)qh) * 2048.0f);
  }
#pragma unroll
  for (int i = 0; i < 8; ++i) {
    half8 vh, vl;
#pragma unroll
    for (int j = 0; j < 8; ++j) { vh[j] = ah[i * 8 + j]; vl[j] = al[i * 8 + j]; }
    *(half8*)(Ah + (size_t)row * 64 + i * 8) = vh;
    *(half8*)(Al + (size_t)row * 64 + i * 8) = vl;
  }
  Bn[row] = 5e-6f * S + 1e-4f;   // rigorous: split err + fp32 accum err
}

// grid (64, 16): x = rowgroup (256 rows), y = split. 4 waves x 64 rows each.
__global__ __launch_bounds__(256, 4) void filter_kernel(const _Float16* __restrict__ Ah,
                                                        const _Float16* __restrict__ Al,
                                                        const _Float16* __restrict__ Bh,
                                                        const _Float16* __restrict__ Bl,
                                                        float* __restrict__ W1,
                                                        float* __restrict__ W2,
                                                        unsigned* __restrict__ I1) {
  const int lane = threadIdx.x & 63;
  const int wave = threadIdx.x >> 6;
  const int split = blockIdx.y;
  const int rowbase = blockIdx.x * 256 + wave * 64;   // 4 rowtiles of 16
  const int c16 = lane & 15, quad = lane >> 4;

  half8 uh0[4], uh1[4], ul0[4], ul1[4];
#pragma unroll
  for (int rt = 0; rt < 4; ++rt) {
    const size_t abase = (size_t)(rowbase + rt * 16 + c16) * 64 + quad * 8;
    uh0[rt] = *(const half8*)(Ah + abase);
    uh1[rt] = *(const half8*)(Ah + abase + 32);
    ul0[rt] = *(const half8*)(Al + abase);
    ul1[rt] = *(const half8*)(Al + abase + 32);
  }

  float a1[4][4], a2[4][4];
  unsigned i1[4][4];
#pragma unroll
  for (int rt = 0; rt < 4; ++rt)
#pragma unroll
    for (int r = 0; r < 4; ++r) { a1[rt][r] = -INFINITY; a2[rt][r] = -INFINITY; i1[rt][r] = 0; }

  const int k0 = split * SPLITK;
#pragma unroll 1
  for (int t = 0; t < NTILES; ++t) {
    const int cb0 = k0 + t * 16;
    const size_t bbase = (size_t)(cb0 + c16) * 64 + quad * 8;
    const half8 vh0 = *(const half8*)(Bh + bbase);
    const half8 vh1 = *(const half8*)(Bh + bbase + 32);
    const half8 vl0 = *(const half8*)(Bl + bbase);
    const half8 vl1 = *(const half8*)(Bl + bbase + 32);
    const unsigned kcur = (unsigned)(cb0 + c16);

#pragma unroll
    for (int rt = 0; rt < 4; ++rt) {
      f32x4 hh = {0.f, 0.f, 0.f, 0.f};
      hh = __builtin_amdgcn_mfma_f32_16x16x32_f16(uh0[rt], vh0, hh, 0, 0, 0);
      hh = __builtin_amdgcn_mfma_f32_16x16x32_f16(uh1[rt], vh1, hh, 0, 0, 0);
      f32x4 xl = {0.f, 0.f, 0.f, 0.f};
      xl = __builtin_amdgcn_mfma_f32_16x16x32_f16(ul0[rt], vh0, xl, 0, 0, 0);
      xl = __builtin_amdgcn_mfma_f32_16x16x32_f16(ul1[rt], vh1, xl, 0, 0, 0);
      xl = __builtin_amdgcn_mfma_f32_16x16x32_f16(uh0[rt], vl0, xl, 0, 0, 0);
      xl = __builtin_amdgcn_mfma_f32_16x16x32_f16(uh1[rt], vl1, xl, 0, 0, 0);
#pragma unroll
      for (int r = 0; r < 4; ++r) {
        const float v = fmaf(xl[r], 1.0f / 2048.0f, hh[r]);
        a2[rt][r] = fmaxf(a2[rt][r], fminf(v, a1[rt][r]));     // new 2nd-best
        const bool gt = v > a1[rt][r];
        a1[rt][r] = fmaxf(a1[rt][r], v);
        i1[rt][r] = gt ? kcur : i1[rt][r];
      }
    }
  }

  // epilogue: reduce top1+top2+idx across the 16 c16 lanes of each quad
#pragma unroll
  for (int rt = 0; rt < 4; ++rt)
#pragma unroll
    for (int r = 0; r < 4; ++r) {
      float x1 = a1[rt][r], x2 = a2[rt][r];
      unsigned xi = i1[rt][r];
#pragma unroll
      for (int off = 1; off < 16; off <<= 1) {
        const float y1 = __shfl_xor(x1, off);
        const float y2 = __shfl_xor(x2, off);
        const unsigned yi = (unsigned)__shfl_xor((int)xi, off);
        x2 = fmaxf(fmaxf(x2, y2), fminf(x1, y1));
        const bool take = (y1 > x1) || (y1 == x1 && yi < xi);
        x1 = fmaxf(x1, y1);
        xi = take ? yi : xi;
      }
      if (c16 == 0) {
        const int row_r = rowbase + rt * 16 + quad * 4 + r;  // C: row=quad*4+reg
        W1[row_r * NSPLIT + split] = x1;
        W2[row_r * NSPLIT + split] = x2;
        I1[row_r * NSPLIT + split] = xi;
      }
    }
}

// exact fp32 score, p/q broadcast from LDS (identical formula to R2/R5)
__device__ __forceinline__ float exact_score(const float4* __restrict__ cb4,
                                             const float4* __restrict__ spq,
                                             int k) {
  float s0 = 0.0f, s1 = 0.0f, s2 = 0.0f, s3 = 0.0f;
#pragma unroll
  for (int m = 0; m < 8; ++m) {
    const float4 cv = cb4[k * 8 + m];
    const float4 pv = spq[m];        // p[4m..4m+3]
    const float4 qv = spq[8 + m];    // q[4m..4m+3]
    s0 = fmaf(cv.x, fmaf(qv.x, cv.x, pv.x), s0);
    s1 = fmaf(cv.y, fmaf(qv.y, cv.y, pv.y), s1);
    s2 = fmaf(cv.z, fmaf(qv.z, cv.z, pv.z), s2);
    s3 = fmaf(cv.w, fmaf(qv.w, cv.w, pv.w), s3);
  }
  return (s0 + s1) + (s2 + s3);
}

// 1 wave per row; 4 rows per block.
__global__ __launch_bounds__(256, 4) void merge_kernel(const float* __restrict__ PQ,
                                                       const float* __restrict__ cb,
                                                       const float* __restrict__ W1,
                                                       const float* __restrict__ W2,
                                                       const unsigned* __restrict__ I1,
                                                       const float* __restrict__ Bn,
                                                       int* __restrict__ idx_final,
                                                       float* __restrict__ out2,
                                                       const double* __restrict__ partials,
                                                       float* __restrict__ out1) {
  __shared__ float4 spq_s[4][16];
  const int lane = threadIdx.x & 63;
  const int wave = threadIdx.x >> 6;
  const int row = blockIdx.x * 4 + wave;

  if (lane < 16)
    spq_s[wave][lane] = ((const float4*)(PQ + (size_t)row * 64))[lane];
  __syncthreads();
  const float4* spq = spq_s[wave];
  const float4* __restrict__ cb4 = (const float4*)cb;

  float a1 = -INFINITY, a2 = -INFINITY;
  unsigned ii = 0;
  if (lane < NSPLIT) {
    a1 = W1[row * NSPLIT + lane];
    a2 = W2[row * NSPLIT + lane];
    ii = I1[row * NSPLIT + lane];
  }
  // A* = wave max of approx winners
  float As = a1;
#pragma unroll
  for (int off = 1; off < 64; off <<= 1) As = fmaxf(As, __shfl_xor(As, off));
  const float T = As - 2.0f * Bn[row];

  float best = -INFINITY;
  int bk = 0x7FFFFFFF;
  if (lane < NSPLIT && a1 >= T) {          // candidate slice winners (~1)
    bk = (int)ii;
    best = exact_score(cb4, spq, bk);
  }
  // full rescans of slices whose runner-up could beat A* (rare)
  unsigned long long mflag = __ballot(lane < NSPLIT && a2 >= T);
#pragma unroll 1
  while (mflag) {
    const int s = __builtin_ctzll(mflag);
    mflag &= mflag - 1;
#pragma unroll 1
    for (int j = 0; j < SPLITK / 64; ++j) {
      const int k = s * SPLITK + lane * (SPLITK / 64) + j;
      const float sc = exact_score(cb4, spq, k);
      if (sc > best || (sc == best && k < bk)) { best = sc; bk = k; }
    }
  }
  // cross-lane argmax, min-k on ties (numpy first-max)
#pragma unroll
  for (int off = 1; off < 64; off <<= 1) {
    const float ov = __shfl_xor(best, off);
    const int ok = __shfl_xor(bk, off);
    if (ov > best || (ov == best && ok < bk)) { best = ov; bk = ok; }
  }
  if (lane == 0) { idx_final[row] = bk; out2[row] = (float)bk; }
  if (blockIdx.x == 0 && threadIdx.x == 0) {
    double s = 0.0;
    for (int i = 0; i < 256; ++i) s += partials[i];
    out1[0] = (float)(s * (1.4426 * 0.5) / (double)NROWS);
  }
}

__global__ __launch_bounds__(256) void gather_kernel(const float* __restrict__ cb,
                                                     const int* __restrict__ idx_final,
                                                     float* __restrict__ out0) {
  const int j = blockIdx.x * 256 + threadIdx.x;  // [0, 524288)
  const int t = j >> 8, r = j & 255;
  const int d = r >> 3, c = r & 7;
  const int n = t * 8 + c;
  out0[j] = cb[idx_final[n] * DIM + d];
}

extern "C" void kernel_launch(void* const* d_in, const int* in_sizes, int n_in,
                              void* d_out, int out_size, void* d_ws, size_t ws_size,
                              hipStream_t stream) {
  const float* z  = (const float*)d_in[0];
  const float* cb = (const float*)d_in[2];   // d_in[1]=noise unused (STE cancels)

  char* ws = (char*)d_ws;
  float*      M1 = (float*)(ws + WS_M1);
  float*      M2 = (float*)(ws + WS_M2);
  double* partials = (double*)(ws + WS_PART);
  float*      PQ = (float*)(ws + WS_PQ);
  float*      Bn = (float*)(ws + WS_BN);
  _Float16*   Ah = (_Float16*)(ws + WS_AH);
  _Float16*   Al = (_Float16*)(ws + WS_AL);
  _Float16*   Bh = (_Float16*)(ws + WS_BH);
  _Float16*   Bl = (_Float16*)(ws + WS_BL);
  float*      W1 = (float*)(ws + WS_W1);
  float*      W2 = (float*)(ws + WS_W2);
  unsigned*   I1 = (unsigned*)(ws + WS_I1);
  int* idx_final = (int*)(ws + WS_IDX);

  float* out0 = (float*)d_out;            // 524288
  float* out1 = out0 + 524288;            // 1
  float* out2 = out1 + 1;                 // 16384

  (void)hipMemsetAsync(ws + WS_M1, 0, 256, stream);           // M1, M2 = 0
  cbprep_kernel<<<KSIZE / 64, 64, 0, stream>>>(cb, Bh, Bl, M1, M2);
  aprep_kernel<<<NROWS / 64, 64, 0, stream>>>(z, M1, M2, PQ, Ah, Al, Bn);
  kl_kernel<<<256, 256, 0, stream>>>(z, partials);
  dim3 fgrid(64, NSPLIT);
  filter_kernel<<<fgrid, 256, 0, stream>>>(Ah, Al, Bh, Bl, W1, W2, I1);
  merge_kernel<<<NROWS / 4, 256, 0, stream>>>(PQ, cb, W1, W2, I1, Bn,
                                              idx_final, out2, partials, out1);
  gather_kernel<<<(NTOK * 256) / 256, 256, 0, stream>>>(cb, idx_final, out0);
}

// Round 7
// 263.730 us; speedup vs baseline: 1.9539x; 1.9539x over previous
//
#include <hip/hip_runtime.h>
#include <math.h>

// ---------------------------------------------------------------------------
// GaussianQuant — MFMA-filtered argmax, R7.
// score[n,k] = sum_d p*c + q*c^2;  u=[p,q], v=[c,c^2], score = u.v  (K=64)
// fp16 hi/lo split (lo x2048):  v ~= uh.vh + (ul.vh + uh.vl)/2048
// Packed select: vq = (bits(v) & 0xFFFFFC00) | klocal  (10-bit k-in-split)
//   -> top1/top2 tracking with NO index registers (4 VALU/value, no spill).
// Rigorous |true - v| <= Bn = 5e-6*S + 1e-4;  quantization adds 2^-13 rel,
// covered in merge by Btot = Bn + 2e-4*(|A*|+1). Merge: T = A* - 2*Btot;
// exact fp32 rescore of slice winners >= T + full rescan of slices whose
// runner-up a2 >= T (provably sound superset of the true argmax).
// ---------------------------------------------------------------------------

typedef _Float16 half8 __attribute__((ext_vector_type(8)));
typedef float f32x4 __attribute__((ext_vector_type(4)));

#define DIM 32
#define NTOK 2048
#define NROWS 16384
#define KSIZE 16384
#define NSPLIT 16
#define SPLITK 1024
#define NTILES 64                      // k-tiles of 16 per split
#define KMASK 0xFFFFFC00u              // clear low 10 bits (SPLITK=1024)

// ws layout (bytes)
#define WS_M1   0                       // 32 float  (written by mfinal)
#define WS_PART 512                     // 256 double (kl partials)
#define WS_MP1  4096                    // 256*32 float = 32 KB
#define WS_PQ   (WS_MP1 + 32768)        // 4 MB
#define WS_BN   (WS_PQ + 4194304)       // 64 KB
#define WS_AH   (WS_BN + 65536)         // 2 MB fp16
#define WS_AL   (WS_AH + 2097152)       // 2 MB
#define WS_BH   (WS_AL + 2097152)       // 2 MB
#define WS_BL   (WS_BH + 2097152)       // 2 MB
#define WS_W1   (WS_BL + 2097152)       // 1 MB
#define WS_W2   (WS_W1 + 1048576)       // 1 MB
#define WS_IDX  (WS_W2 + 1048576)       // 64 KB

__global__ __launch_bounds__(256) void kl_kernel(const float* __restrict__ z,
                                                 double* __restrict__ partials) {
  const int tid = threadIdx.x;
  const int lane = tid & 63;
  const int wave = tid >> 6;
  double s = 0.0;
  for (int j = blockIdx.x * 256 + tid; j < NTOK * 256; j += 256 * 256) {
    const int t = j >> 8, r = j & 255;
    float mu = z[t * 512 + r];
    float lv = z[t * 512 + 256 + r];
    lv = fminf(fmaxf(lv, -30.0f), 20.0f);
    float var = expf(lv);
    s += (double)(mu * mu + var - 1.0f - lv);
  }
  for (int off = 32; off > 0; off >>= 1) s += __shfl_down(s, off);
  __shared__ double wsum[4];
  if (lane == 0) wsum[wave] = s;
  __syncthreads();
  if (tid == 0) partials[blockIdx.x] = (wsum[0] + wsum[1]) + (wsum[2] + wsum[3]);
}

// per-dim |c| max, stage 1: 256 blocks x 64 rows each -> MP1[block][32]
__global__ __launch_bounds__(256) void mpartial_kernel(const float* __restrict__ cb,
                                                       float* __restrict__ MP1) {
  __shared__ float lm[8][DIM];
  const int d = threadIdx.x & 31;
  const int g = threadIdx.x >> 5;      // 8 groups of 8 rows
  float m = 0.0f;
#pragma unroll
  for (int i = 0; i < 8; ++i) {
    const int r = blockIdx.x * 64 + g * 8 + i;
    m = fmaxf(m, fabsf(cb[r * DIM + d]));
  }
  lm[g][d] = m;
  __syncthreads();
  if (g == 0) {
    float x = lm[0][d];
#pragma unroll
    for (int i = 1; i < 8; ++i) x = fmaxf(x, lm[i][d]);
    MP1[blockIdx.x * DIM + d] = x;
  }
}

// stage 2: reduce 256 partials -> M1[32]
__global__ __launch_bounds__(256) void mfinal_kernel(const float* __restrict__ MP1,
                                                     float* __restrict__ M1) {
  __shared__ float lm[8][DIM];
  const int d = threadIdx.x & 31;
  const int g = threadIdx.x >> 5;
  float m = 0.0f;
  for (int i = g; i < 256; i += 8) m = fmaxf(m, MP1[i * DIM + d]);
  lm[g][d] = m;
  __syncthreads();
  if (g == 0) {
    float x = lm[0][d];
#pragma unroll
    for (int i = 1; i < 8; ++i) x = fmaxf(x, lm[i][d]);
    M1[d] = x;
  }
}

// pack codebook into fp16 hi/lo [k][64]: wave handles 2 rows, lane = dim
__global__ __launch_bounds__(256) void cbpack_kernel(const float* __restrict__ cb,
                                                     _Float16* __restrict__ Bh,
                                                     _Float16* __restrict__ Bl) {
  const int wave = threadIdx.x >> 6;
  const int lane = threadIdx.x & 63;
  const int k = blockIdx.x * 8 + wave * 2 + (lane >> 5);
  const int d = lane & 31;
  const float c = cb[k * DIM + d];
  const float c2 = c * c;
  const _Float16 ch = (_Float16)c;
  const _Float16 sh = (_Float16)c2;
  Bh[(size_t)k * 64 + d] = ch;
  Bh[(size_t)k * 64 + 32 + d] = sh;
  Bl[(size_t)k * 64 + d] = (_Float16)((c - (float)ch) * 2048.0f);
  Bl[(size_t)k * 64 + 32 + d] = (_Float16)((c2 - (float)sh) * 2048.0f);
}

// per-row p,q + fp16 hi/lo pack + error bound. wave handles 2 rows.
__global__ __launch_bounds__(256) void aprep_kernel(const float* __restrict__ z,
                                                    const float* __restrict__ M1,
                                                    float* __restrict__ PQ,
                                                    _Float16* __restrict__ Ah,
                                                    _Float16* __restrict__ Al,
                                                    float* __restrict__ Bn) {
  const int wave = threadIdx.x >> 6;
  const int lane = threadIdx.x & 63;
  const int row = blockIdx.x * 8 + wave * 2 + (lane >> 5);
  const int d = lane & 31;
  const int t = row >> 3, c = row & 7;

  const float mu = z[t * 512 + d * 8 + c];
  float lv = z[t * 512 + 256 + d * 8 + c];
  lv = fminf(fmaxf(lv, -30.0f), 20.0f);
  const float stdv = expf(0.5f * lv);
  const float iv = 1.0f / (stdv * stdv);       // identical to R2 expression
  const float p = mu * iv;
  const float q = 0.5f * (1.0f - iv);
  PQ[(size_t)row * 64 + d] = p;
  PQ[(size_t)row * 64 + 32 + d] = q;
  const _Float16 ph = (_Float16)p;
  const _Float16 qh = (_Float16)q;
  Ah[(size_t)row * 64 + d] = ph;
  Ah[(size_t)row * 64 + 32 + d] = qh;
  Al[(size_t)row * 64 + d] = (_Float16)((p - (float)ph) * 2048.0f);
  Al[(size_t)row * 64 + 32 + d] = (_Float16)((q - (float)qh) * 2048.0f);

  const float m1 = M1[d];
  float s = fabsf(p) * m1 + fabsf(q) * m1 * m1;
#pragma unroll
  for (int off = 1; off < 32; off <<= 1) s += __shfl_xor(s, off);  // within 32
  if ((lane & 31) == 0) Bn[row] = 5e-6f * s + 1e-4f;
}

// grid (64, 16): x = rowgroup (256 rows), y = split. 4 waves x 64 rows each.
__global__ __launch_bounds__(256, 3) void filter_kernel(const _Float16* __restrict__ Ah,
                                                        const _Float16* __restrict__ Al,
                                                        const _Float16* __restrict__ Bh,
                                                        const _Float16* __restrict__ Bl,
                                                        float* __restrict__ W1,
                                                        float* __restrict__ W2) {
  const int lane = threadIdx.x & 63;
  const int wave = threadIdx.x >> 6;
  const int split = blockIdx.y;
  const int rowbase = blockIdx.x * 256 + wave * 64;   // 4 rowtiles of 16
  const int c16 = lane & 15, quad = lane >> 4;

  half8 uh0[4], uh1[4], ul0[4], ul1[4];
#pragma unroll
  for (int rt = 0; rt < 4; ++rt) {
    const size_t abase = (size_t)(rowbase + rt * 16 + c16) * 64 + quad * 8;
    uh0[rt] = *(const half8*)(Ah + abase);
    uh1[rt] = *(const half8*)(Ah + abase + 32);
    ul0[rt] = *(const half8*)(Al + abase);
    ul1[rt] = *(const half8*)(Al + abase + 32);
  }

  float a1[4][4], a2[4][4];
#pragma unroll
  for (int rt = 0; rt < 4; ++rt)
#pragma unroll
    for (int r = 0; r < 4; ++r) { a1[rt][r] = -INFINITY; a2[rt][r] = -INFINITY; }

  const int k0 = split * SPLITK;
#pragma unroll 1
  for (int t = 0; t < NTILES; ++t) {
    const int cb0 = k0 + t * 16;
    const size_t bbase = (size_t)(cb0 + c16) * 64 + quad * 8;
    const half8 vh0 = *(const half8*)(Bh + bbase);
    const half8 vh1 = *(const half8*)(Bh + bbase + 32);
    const half8 vl0 = *(const half8*)(Bl + bbase);
    const half8 vl1 = *(const half8*)(Bl + bbase + 32);
    const unsigned kq = (unsigned)(t * 16 + c16);   // 10-bit k-in-split

#pragma unroll
    for (int rt = 0; rt < 4; ++rt) {
      f32x4 hh = {0.f, 0.f, 0.f, 0.f};
      hh = __builtin_amdgcn_mfma_f32_16x16x32_f16(uh0[rt], vh0, hh, 0, 0, 0);
      hh = __builtin_amdgcn_mfma_f32_16x16x32_f16(uh1[rt], vh1, hh, 0, 0, 0);
      f32x4 xl = {0.f, 0.f, 0.f, 0.f};
      xl = __builtin_amdgcn_mfma_f32_16x16x32_f16(ul0[rt], vh0, xl, 0, 0, 0);
      xl = __builtin_amdgcn_mfma_f32_16x16x32_f16(ul1[rt], vh1, xl, 0, 0, 0);
      xl = __builtin_amdgcn_mfma_f32_16x16x32_f16(uh0[rt], vl0, xl, 0, 0, 0);
      xl = __builtin_amdgcn_mfma_f32_16x16x32_f16(uh1[rt], vl1, xl, 0, 0, 0);
#pragma unroll
      for (int r = 0; r < 4; ++r) {
        const float v = fmaf(xl[r], 1.0f / 2048.0f, hh[r]);
        const float vq = __uint_as_float((__float_as_uint(v) & KMASK) | kq);
        a2[rt][r] = fmaxf(a2[rt][r], fminf(vq, a1[rt][r]));   // med3 idiom
        a1[rt][r] = fmaxf(a1[rt][r], vq);
      }
    }
  }

  // reduce packed top1+top2 across the 16 c16 lanes of each quad
#pragma unroll
  for (int rt = 0; rt < 4; ++rt)
#pragma unroll
    for (int r = 0; r < 4; ++r) {
      float x1 = a1[rt][r], x2 = a2[rt][r];
#pragma unroll
      for (int off = 1; off < 16; off <<= 1) {
        const float y1 = __shfl_xor(x1, off);
        const float y2 = __shfl_xor(x2, off);
        x2 = fmaxf(fmaxf(x2, y2), fminf(x1, y1));
        x1 = fmaxf(x1, y1);
      }
      if (c16 == 0) {
        const int row_r = rowbase + rt * 16 + quad * 4 + r;  // C: row=quad*4+reg
        W1[row_r * NSPLIT + split] = x1;
        W2[row_r * NSPLIT + split] = x2;
      }
    }
}

// exact fp32 score, p/q broadcast from LDS (identical formula to R2)
__device__ __forceinline__ float exact_score(const float4* __restrict__ cb4,
                                             const float4* __restrict__ spq,
                                             int k) {
  float s0 = 0.0f, s1 = 0.0f, s2 = 0.0f, s3 = 0.0f;
#pragma unroll
  for (int m = 0; m < 8; ++m) {
    const float4 cv = cb4[k * 8 + m];
    const float4 pv = spq[m];        // p[4m..4m+3]
    const float4 qv = spq[8 + m];    // q[4m..4m+3]
    s0 = fmaf(cv.x, fmaf(qv.x, cv.x, pv.x), s0);
    s1 = fmaf(cv.y, fmaf(qv.y, cv.y, pv.y), s1);
    s2 = fmaf(cv.z, fmaf(qv.z, cv.z, pv.z), s2);
    s3 = fmaf(cv.w, fmaf(qv.w, cv.w, pv.w), s3);
  }
  return (s0 + s1) + (s2 + s3);
}

// 1 wave per row; 4 rows per block.
__global__ __launch_bounds__(256, 4) void merge_kernel(const float* __restrict__ PQ,
                                                       const float* __restrict__ cb,
                                                       const float* __restrict__ W1,
                                                       const float* __restrict__ W2,
                                                       const float* __restrict__ Bn,
                                                       int* __restrict__ idx_final,
                                                       float* __restrict__ out2,
                                                       const double* __restrict__ partials,
                                                       float* __restrict__ out1) {
  __shared__ float4 spq_s[4][16];
  const int lane = threadIdx.x & 63;
  const int wave = threadIdx.x >> 6;
  const int row = blockIdx.x * 4 + wave;

  if (lane < 16)
    spq_s[wave][lane] = ((const float4*)(PQ + (size_t)row * 64))[lane];
  __syncthreads();
  const float4* spq = spq_s[wave];
  const float4* __restrict__ cb4 = (const float4*)cb;

  float a1 = -INFINITY, a2 = -INFINITY;
  if (lane < NSPLIT) {
    a1 = W1[row * NSPLIT + lane];
    a2 = W2[row * NSPLIT + lane];
  }
  float As = a1;
#pragma unroll
  for (int off = 1; off < 64; off <<= 1) As = fmaxf(As, __shfl_xor(As, off));
  const float Btot = Bn[row] + 2e-4f * (fabsf(As) + 1.0f);  // + quantization
  const float T = As - 2.0f * Btot;

  float best = -INFINITY;
  int bk = 0x7FFFFFFF;
  if (lane < NSPLIT && a1 >= T) {              // candidate slice winners (~1)
    bk = lane * SPLITK + (int)(__float_as_uint(a1) & 1023u);
    best = exact_score(cb4, spq, bk);
  }
  unsigned long long mflag = __ballot(lane < NSPLIT && a2 >= T);
#pragma unroll 1
  while (mflag) {
    const int s = __builtin_ctzll(mflag);
    mflag &= mflag - 1;
#pragma unroll 1
    for (int j = 0; j < SPLITK / 64; ++j) {
      const int k = s * SPLITK + lane * (SPLITK / 64) + j;
      const float sc = exact_score(cb4, spq, k);
      if (sc > best || (sc == best && k < bk)) { best = sc; bk = k; }
    }
  }
  // cross-lane argmax, min-k on ties (numpy first-max)
#pragma unroll
  for (int off = 1; off < 64; off <<= 1) {
    const float ov = __shfl_xor(best, off);
    const int ok = __shfl_xor(bk, off);
    if (ov > best || (ov == best && ok < bk)) { best = ov; bk = ok; }
  }
  if (lane == 0) { idx_final[row] = bk; out2[row] = (float)bk; }
  if (blockIdx.x == 0 && threadIdx.x == 0) {
    double s = 0.0;
    for (int i = 0; i < 256; ++i) s += partials[i];
    out1[0] = (float)(s * (1.4426 * 0.5) / (double)NROWS);
  }
}

__global__ __launch_bounds__(256) void gather_kernel(const float* __restrict__ cb,
                                                     const int* __restrict__ idx_final,
                                                     float* __restrict__ out0) {
  const int j = blockIdx.x * 256 + threadIdx.x;  // [0, 524288)
  const int t = j >> 8, r = j & 255;
  const int d = r >> 3, c = r & 7;
  const int n = t * 8 + c;
  out0[j] = cb[idx_final[n] * DIM + d];
}

extern "C" void kernel_launch(void* const* d_in, const int* in_sizes, int n_in,
                              void* d_out, int out_size, void* d_ws, size_t ws_size,
                              hipStream_t stream) {
  const float* z  = (const float*)d_in[0];
  const float* cb = (const float*)d_in[2];   // d_in[1]=noise unused (STE cancels)

  char* ws = (char*)d_ws;
  float*      M1 = (float*)(ws + WS_M1);
  double* partials = (double*)(ws + WS_PART);
  float*     MP1 = (float*)(ws + WS_MP1);
  float*      PQ = (float*)(ws + WS_PQ);
  float*      Bn = (float*)(ws + WS_BN);
  _Float16*   Ah = (_Float16*)(ws + WS_AH);
  _Float16*   Al = (_Float16*)(ws + WS_AL);
  _Float16*   Bh = (_Float16*)(ws + WS_BH);
  _Float16*   Bl = (_Float16*)(ws + WS_BL);
  float*      W1 = (float*)(ws + WS_W1);
  float*      W2 = (float*)(ws + WS_W2);
  int* idx_final = (int*)(ws + WS_IDX);

  float* out0 = (float*)d_out;            // 524288
  float* out1 = out0 + 524288;            // 1
  float* out2 = out1 + 1;                 // 16384

  mpartial_kernel<<<256, 256, 0, stream>>>(cb, MP1);
  mfinal_kernel<<<1, 256, 0, stream>>>(MP1, M1);
  cbpack_kernel<<<KSIZE / 8, 256, 0, stream>>>(cb, Bh, Bl);
  aprep_kernel<<<NROWS / 8, 256, 0, stream>>>(z, M1, PQ, Ah, Al, Bn);
  kl_kernel<<<256, 256, 0, stream>>>(z, partials);
  dim3 fgrid(64, NSPLIT);
  filter_kernel<<<fgrid, 256, 0, stream>>>(Ah, Al, Bh, Bl, W1, W2);
  merge_kernel<<<NROWS / 4, 256, 0, stream>>>(PQ, cb, W1, W2, Bn,
                                              idx_final, out2, partials, out1);
  gather_kernel<<<(NTOK * 256) / 256, 256, 0, stream>>>(cb, idx_final, out0);
}

// Round 8
// 239.261 us; speedup vs baseline: 2.1537x; 1.1023x over previous
//
#include <hip/hip_runtime.h>
#include <math.h>

// ---------------------------------------------------------------------------
// GaussianQuant — MFMA-filtered argmax, R8.
// score[n,k] = sum_d p*c + q*c^2;  u=[p,q], v=[c,c^2], score = u.v  (K=64)
// fp16 hi/lo split (lo x2048):  v ~= uh.vh + (ul.vh + uh.vl)/2048
// Packed select: vq = (bits(v) & 0xFFFFFC00) | k_in_split  (10 bits).
// Rigorous |true - v| <= Bn = 5e-6*S + 1e-4;  pack-quantization covered by
// Btot = Bn + 2e-4*(|A*|+1). Merge: T = A* - 2*Btot; exact fp32 rescore of
// slice winners >= T + full rescan of slices with runner-up a2 >= T.
// R8: ping-pong B prefetch in filter (L2-latency was the R7 bottleneck);
// fused M1-max into cbpack, KL into aprep, gather+out1 into merge.
// ---------------------------------------------------------------------------

typedef _Float16 half8 __attribute__((ext_vector_type(8)));
typedef float f32x4 __attribute__((ext_vector_type(4)));

#define DIM 32
#define NTOK 2048
#define NROWS 16384
#define KSIZE 16384
#define NSPLIT 16
#define SPLITK 1024
#define NTILES 64                      // k-tiles of 16 per split
#define KMASK 0xFFFFFC00u              // clear low 10 bits (SPLITK=1024)

// ws layout (bytes); [0,4096) zeroed by memset each launch
#define WS_M1   0                       // 32 float (atomicMax targets)
#define WS_KL   256                     // 1 double (atomicAdd target)
#define WS_PQ   4096                    // 4 MB
#define WS_BN   (WS_PQ + 4194304)       // 64 KB
#define WS_AH   (WS_BN + 65536)         // 2 MB fp16
#define WS_AL   (WS_AH + 2097152)       // 2 MB
#define WS_BH   (WS_AL + 2097152)       // 2 MB
#define WS_BL   (WS_BH + 2097152)       // 2 MB
#define WS_W1   (WS_BL + 2097152)       // 1 MB
#define WS_W2   (WS_W1 + 1048576)       // 1 MB

// pack codebook to fp16 hi/lo + per-dim |c| max (256 blocks x 64 k-rows)
__global__ __launch_bounds__(256) void cbpack_kernel(const float* __restrict__ cb,
                                                     _Float16* __restrict__ Bh,
                                                     _Float16* __restrict__ Bl,
                                                     float* __restrict__ M1) {
  __shared__ float lm[8][DIM];
  const int w = threadIdx.x >> 6, l = threadIdx.x & 63;
  const int sub = l >> 5, d = l & 31;
  float m = 0.0f;
#pragma unroll
  for (int i = 0; i < 8; ++i) {
    const int k = blockIdx.x * 64 + i * 8 + w * 2 + sub;
    const float c = cb[k * DIM + d];
    const float c2 = c * c;
    const _Float16 ch = (_Float16)c;
    const _Float16 sh = (_Float16)c2;
    Bh[(size_t)k * 64 + d] = ch;
    Bh[(size_t)k * 64 + 32 + d] = sh;
    Bl[(size_t)k * 64 + d] = (_Float16)((c - (float)ch) * 2048.0f);
    Bl[(size_t)k * 64 + 32 + d] = (_Float16)((c2 - (float)sh) * 2048.0f);
    m = fmaxf(m, fabsf(c));
  }
  lm[threadIdx.x >> 5][d] = m;
  __syncthreads();
  if (threadIdx.x < DIM) {
    float x = lm[0][threadIdx.x];
#pragma unroll
    for (int i = 1; i < 8; ++i) x = fmaxf(x, lm[i][threadIdx.x]);
    atomicMax((unsigned*)&M1[threadIdx.x], __float_as_uint(x));
  }
}

// per-row p,q + fp16 hi/lo pack + error bound + fused KL sum
__global__ __launch_bounds__(256) void aprep_kernel(const float* __restrict__ z,
                                                    const float* __restrict__ M1,
                                                    float* __restrict__ PQ,
                                                    _Float16* __restrict__ Ah,
                                                    _Float16* __restrict__ Al,
                                                    float* __restrict__ Bn,
                                                    double* __restrict__ klsum) {
  const int w = threadIdx.x >> 6, l = threadIdx.x & 63;
  const int sub = l >> 5, d = l & 31;
  const float m1 = M1[d];
  double kacc = 0.0;
#pragma unroll 1
  for (int i = 0; i < 8; ++i) {
    const int row = blockIdx.x * 64 + i * 8 + w * 2 + sub;
    const int t = row >> 3, c = row & 7;
    const float mu = z[t * 512 + d * 8 + c];
    float lv = z[t * 512 + 256 + d * 8 + c];
    lv = fminf(fmaxf(lv, -30.0f), 20.0f);
    const float stdv = expf(0.5f * lv);
    const float iv = 1.0f / (stdv * stdv);     // identical to R2 expression
    const float p = mu * iv;
    const float q = 0.5f * (1.0f - iv);
    PQ[(size_t)row * 64 + d] = p;
    PQ[(size_t)row * 64 + 32 + d] = q;
    const _Float16 ph = (_Float16)p;
    const _Float16 qh = (_Float16)q;
    Ah[(size_t)row * 64 + d] = ph;
    Ah[(size_t)row * 64 + 32 + d] = qh;
    Al[(size_t)row * 64 + d] = (_Float16)((p - (float)ph) * 2048.0f);
    Al[(size_t)row * 64 + 32 + d] = (_Float16)((q - (float)qh) * 2048.0f);
    kacc += (double)(mu * mu + stdv * stdv - 1.0f - lv);
    float s = fabsf(p) * m1 + fabsf(q) * m1 * m1;
#pragma unroll
    for (int off = 1; off < 32; off <<= 1) s += __shfl_xor(s, off);
    if ((l & 31) == 0) Bn[row] = 5e-6f * s + 1e-4f;
  }
#pragma unroll
  for (int off = 32; off > 0; off >>= 1) kacc += __shfl_down(kacc, off);
  __shared__ double wsum[4];
  if (l == 0) wsum[w] = kacc;
  __syncthreads();
  if (threadIdx.x == 0)
    atomicAdd(klsum, (wsum[0] + wsum[1]) + (wsum[2] + wsum[3]));
}

#define FTILE(VH0, VH1, VL0, VL1, KQ)                                         \
  {                                                                           \
    const unsigned kq_ = (KQ);                                                \
    _Pragma("unroll")                                                         \
    for (int rt = 0; rt < 4; ++rt) {                                          \
      f32x4 hh = {0.f, 0.f, 0.f, 0.f};                                        \
      hh = __builtin_amdgcn_mfma_f32_16x16x32_f16(uh0[rt], VH0, hh, 0, 0, 0); \
      hh = __builtin_amdgcn_mfma_f32_16x16x32_f16(uh1[rt], VH1, hh, 0, 0, 0); \
      f32x4 xc = {0.f, 0.f, 0.f, 0.f};                                        \
      xc = __builtin_amdgcn_mfma_f32_16x16x32_f16(ul0[rt], VH0, xc, 0, 0, 0); \
      xc = __builtin_amdgcn_mfma_f32_16x16x32_f16(ul1[rt], VH1, xc, 0, 0, 0); \
      xc = __builtin_amdgcn_mfma_f32_16x16x32_f16(uh0[rt], VL0, xc, 0, 0, 0); \
      xc = __builtin_amdgcn_mfma_f32_16x16x32_f16(uh1[rt], VL1, xc, 0, 0, 0); \
      _Pragma("unroll")                                                       \
      for (int r = 0; r < 4; ++r) {                                           \
        const float v = fmaf(xc[r], 1.0f / 2048.0f, hh[r]);                   \
        const float vq = __uint_as_float((__float_as_uint(v) & KMASK) | kq_); \
        a2[rt][r] = fmaxf(a2[rt][r], fminf(vq, a1[rt][r]));                   \
        a1[rt][r] = fmaxf(a1[rt][r], vq);                                     \
      }                                                                       \
    }                                                                         \
  }

// grid (64, 16): x = rowgroup (256 rows), y = split. 4 waves x 64 rows each.
__global__ __launch_bounds__(256, 2) void filter_kernel(const _Float16* __restrict__ Ah,
                                                        const _Float16* __restrict__ Al,
                                                        const _Float16* __restrict__ Bh,
                                                        const _Float16* __restrict__ Bl,
                                                        float* __restrict__ W1,
                                                        float* __restrict__ W2) {
  const int lane = threadIdx.x & 63;
  const int wave = threadIdx.x >> 6;
  const int split = blockIdx.y;
  const int rowbase = blockIdx.x * 256 + wave * 64;   // 4 rowtiles of 16
  const int c16 = lane & 15, quad = lane >> 4;
  const unsigned c16u = (unsigned)c16;

  half8 uh0[4], uh1[4], ul0[4], ul1[4];
#pragma unroll
  for (int rt = 0; rt < 4; ++rt) {
    const size_t abase = (size_t)(rowbase + rt * 16 + c16) * 64 + quad * 8;
    uh0[rt] = *(const half8*)(Ah + abase);
    uh1[rt] = *(const half8*)(Ah + abase + 32);
    ul0[rt] = *(const half8*)(Al + abase);
    ul1[rt] = *(const half8*)(Al + abase + 32);
  }

  float a1[4][4], a2[4][4];
#pragma unroll
  for (int rt = 0; rt < 4; ++rt)
#pragma unroll
    for (int r = 0; r < 4; ++r) { a1[rt][r] = -INFINITY; a2[rt][r] = -INFINITY; }

  const int k0 = split * SPLITK;
  const _Float16* pbh = Bh + (size_t)(k0 + c16) * 64 + quad * 8;
  const _Float16* pbl = Bl + (size_t)(k0 + c16) * 64 + quad * 8;

  // ping-pong prefetch: tile stride = 16 k * 64 halfs = 1024
  half8 bxh0 = *(const half8*)(pbh);
  half8 bxh1 = *(const half8*)(pbh + 32);
  half8 bxl0 = *(const half8*)(pbl);
  half8 bxl1 = *(const half8*)(pbl + 32);
#pragma unroll 1
  for (int t = 0; t < NTILES; t += 2) {
    const _Float16* p1h = pbh + (size_t)(t + 1) * 1024;
    const _Float16* p1l = pbl + (size_t)(t + 1) * 1024;
    const half8 byh0 = *(const half8*)(p1h);
    const half8 byh1 = *(const half8*)(p1h + 32);
    const half8 byl0 = *(const half8*)(p1l);
    const half8 byl1 = *(const half8*)(p1l + 32);
    FTILE(bxh0, bxh1, bxl0, bxl1, (unsigned)(t * 16) + c16u);
    const _Float16* p2h = pbh + (size_t)(t + 2) * 1024;   // harmless 2KB
    const _Float16* p2l = pbl + (size_t)(t + 2) * 1024;   // over-read at end
    bxh0 = *(const half8*)(p2h);
    bxh1 = *(const half8*)(p2h + 32);
    bxl0 = *(const half8*)(p2l);
    bxl1 = *(const half8*)(p2l + 32);
    FTILE(byh0, byh1, byl0, byl1, (unsigned)((t + 1) * 16) + c16u);
  }

  // reduce packed top1+top2 across the 16 c16 lanes of each quad
#pragma unroll
  for (int rt = 0; rt < 4; ++rt)
#pragma unroll
    for (int r = 0; r < 4; ++r) {
      float x1 = a1[rt][r], x2 = a2[rt][r];
#pragma unroll
      for (int off = 1; off < 16; off <<= 1) {
        const float y1 = __shfl_xor(x1, off);
        const float y2 = __shfl_xor(x2, off);
        x2 = fmaxf(fmaxf(x2, y2), fminf(x1, y1));
        x1 = fmaxf(x1, y1);
      }
      if (c16 == 0) {
        const int row_r = rowbase + rt * 16 + quad * 4 + r;  // C: row=quad*4+reg
        W1[row_r * NSPLIT + split] = x1;
        W2[row_r * NSPLIT + split] = x2;
      }
    }
}

// exact fp32 score, p/q broadcast from LDS (identical formula to R2)
__device__ __forceinline__ float exact_score(const float4* __restrict__ cb4,
                                             const float4* __restrict__ spq,
                                             int k) {
  float s0 = 0.0f, s1 = 0.0f, s2 = 0.0f, s3 = 0.0f;
#pragma unroll
  for (int m = 0; m < 8; ++m) {
    const float4 cv = cb4[k * 8 + m];
    const float4 pv = spq[m];        // p[4m..4m+3]
    const float4 qv = spq[8 + m];    // q[4m..4m+3]
    s0 = fmaf(cv.x, fmaf(qv.x, cv.x, pv.x), s0);
    s1 = fmaf(cv.y, fmaf(qv.y, cv.y, pv.y), s1);
    s2 = fmaf(cv.z, fmaf(qv.z, cv.z, pv.z), s2);
    s3 = fmaf(cv.w, fmaf(qv.w, cv.w, pv.w), s3);
  }
  return (s0 + s1) + (s2 + s3);
}

// 1 wave per row; 4 rows per block. Fused: exact re-argmax + out2 + gather
// (out0) + out1 (kl scalar).
__global__ __launch_bounds__(256, 4) void merge_kernel(const float* __restrict__ PQ,
                                                       const float* __restrict__ cb,
                                                       const float* __restrict__ W1,
                                                       const float* __restrict__ W2,
                                                       const float* __restrict__ Bn,
                                                       const double* __restrict__ klsum,
                                                       float* __restrict__ out0,
                                                       float* __restrict__ out1,
                                                       float* __restrict__ out2) {
  __shared__ float4 spq_s[4][16];
  const int lane = threadIdx.x & 63;
  const int wave = threadIdx.x >> 6;
  const int row = blockIdx.x * 4 + wave;

  if (lane < 16)
    spq_s[wave][lane] = ((const float4*)(PQ + (size_t)row * 64))[lane];
  __syncthreads();
  const float4* spq = spq_s[wave];
  const float4* __restrict__ cb4 = (const float4*)cb;

  float a1 = -INFINITY, a2 = -INFINITY;
  if (lane < NSPLIT) {
    a1 = W1[row * NSPLIT + lane];
    a2 = W2[row * NSPLIT + lane];
  }
  float As = a1;
#pragma unroll
  for (int off = 1; off < 64; off <<= 1) As = fmaxf(As, __shfl_xor(As, off));
  const float Btot = Bn[row] + 2e-4f * (fabsf(As) + 1.0f);  // + quantization
  const float T = As - 2.0f * Btot;

  float best = -INFINITY;
  int bk = 0x7FFFFFFF;
  if (lane < NSPLIT && a1 >= T) {              // candidate slice winners (~1)
    bk = lane * SPLITK + (int)(__float_as_uint(a1) & 1023u);
    best = exact_score(cb4, spq, bk);
  }
  unsigned long long mflag = __ballot(lane < NSPLIT && a2 >= T);
#pragma unroll 1
  while (mflag) {
    const int s = __builtin_ctzll(mflag);
    mflag &= mflag - 1;
#pragma unroll 1
    for (int j = 0; j < SPLITK / 64; ++j) {
      const int k = s * SPLITK + lane * (SPLITK / 64) + j;
      const float sc = exact_score(cb4, spq, k);
      if (sc > best || (sc == best && k < bk)) { best = sc; bk = k; }
    }
  }
  // cross-lane argmax, min-k on ties (numpy first-max)
#pragma unroll
  for (int off = 1; off < 64; off <<= 1) {
    const float ov = __shfl_xor(best, off);
    const int ok = __shfl_xor(bk, off);
    if (ov > best || (ov == best && ok < bk)) { best = ov; bk = ok; }
  }
  if (lane == 0) out2[row] = (float)bk;
  const int tt = row >> 3, cc = row & 7;
  if (lane < DIM) out0[tt * 256 + lane * 8 + cc] = cb[bk * DIM + lane];
  if (blockIdx.x == 0 && threadIdx.x == 0)
    out1[0] = (float)(klsum[0] * (1.4426 * 0.5) / (double)NROWS);
}

extern "C" void kernel_launch(void* const* d_in, const int* in_sizes, int n_in,
                              void* d_out, int out_size, void* d_ws, size_t ws_size,
                              hipStream_t stream) {
  const float* z  = (const float*)d_in[0];
  const float* cb = (const float*)d_in[2];   // d_in[1]=noise unused (STE cancels)

  char* ws = (char*)d_ws;
  float*      M1 = (float*)(ws + WS_M1);
  double* klsum  = (double*)(ws + WS_KL);
  float*      PQ = (float*)(ws + WS_PQ);
  float*      Bn = (float*)(ws + WS_BN);
  _Float16*   Ah = (_Float16*)(ws + WS_AH);
  _Float16*   Al = (_Float16*)(ws + WS_AL);
  _Float16*   Bh = (_Float16*)(ws + WS_BH);
  _Float16*   Bl = (_Float16*)(ws + WS_BL);
  float*      W1 = (float*)(ws + WS_W1);
  float*      W2 = (float*)(ws + WS_W2);

  float* out0 = (float*)d_out;            // 524288
  float* out1 = out0 + 524288;            // 1
  float* out2 = out1 + 1;                 // 16384

  (void)hipMemsetAsync(ws, 0, 4096, stream);       // M1, klsum = 0
  cbpack_kernel<<<KSIZE / 64, 256, 0, stream>>>(cb, Bh, Bl, M1);
  aprep_kernel<<<NROWS / 64, 256, 0, stream>>>(z, M1, PQ, Ah, Al, Bn, klsum);
  dim3 fgrid(64, NSPLIT);
  filter_kernel<<<fgrid, 256, 0, stream>>>(Ah, Al, Bh, Bl, W1, W2);
  merge_kernel<<<NROWS / 4, 256, 0, stream>>>(PQ, cb, W1, W2, Bn, klsum,
                                              out0, out1, out2);
}